// Round 9
// baseline (280.919 us; speedup 1.0000x reference)
//
#include <hip/hip_runtime.h>
#include <hip/hip_cooperative_groups.h>
#include <math.h>

#define WID 512
#define HEI 512
#define NB  16
#define HW  ((size_t)HEI * WID)
#define NEG_INF (-INFINITY)

typedef float f4 __attribute__((ext_vector_type(4)));
namespace cg = cooperative_groups;

#define NTL(p) __builtin_nontemporal_load(p)

__device__ __forceinline__ float qmax4(f4 v) {
    return fmaxf(fmaxf(v.x, v.y), fmaxf(v.z, v.w));
}

__device__ __forceinline__ f4 min3v(f4 a, f4 b, f4 c) {
    f4 v;
    v.x = fminf(fminf(a.x, b.x), c.x);
    v.y = fminf(fminf(a.y, b.y), c.y);
    v.z = fminf(fminf(a.z, b.z), c.z);
    v.w = fminf(fminf(a.w, b.w), c.w);
    return v;
}

// Horizontal 35-max: output cols 4*c4+d (d=0..3); reads f4 [c4, c4+10]
// (sm float x = image col x-20; halo = -inf). HW-verified R5/R7 (absmax=0.0).
__device__ __forceinline__ f4 hwin35(const f4* __restrict__ rp, int c4) {
    f4 vv[11];
    #pragma unroll
    for (int i = 0; i < 11; ++i) vv[i] = rp[c4 + i];
    float q[10];
    #pragma unroll
    for (int i = 1; i <= 9; ++i) q[i] = qmax4(vv[i]);
    float Q28 = fmaxf(fmaxf(fmaxf(q[2], q[3]), fmaxf(q[4], q[5])),
                      fmaxf(fmaxf(q[6], q[7]), q[8]));
    float Q18 = fmaxf(Q28, q[1]);
    float Q29 = fmaxf(Q28, q[9]);
    float s01 = fmaxf(vv[9].x, vv[9].y);
    float s23 = fmaxf(vv[1].z, vv[1].w);
    f4 o;
    o.x = fmaxf(fmaxf(Q18, vv[0].w), s01);
    o.y = fmaxf(Q18, fmaxf(s01, vv[9].z));
    o.z = fmaxf(fmaxf(Q29, vv[1].y), s23);
    o.w = fmaxf(Q29, fmaxf(s23, vv[10].x));
    return o;
}

// -------------------------------------------------------------------------
// Single cooperative kernel, grid 512 x 256 thr (<= 3 blk/CU capacity at
// 41.5 KB LDS -> co-residency guaranteed).
// Phase 1 (hmax, R7 math): block bx covers z = bx>>4, rows (bx&15)*32..+31,
//   8 tasks of 4 rows (1 row/wave); next task's 6 NT f4 loads issued before
//   the barrier (register ping-pong, one barrier/task).
// grid.sync() (+threadfence) replaces the kernel boundary.
// Phase 2 (vmax, R7 128-tall verbatim): bx -> (wt=bx&7, ht=(bx>>3)&3,
//   b=bx>>5); ticket finalize (tk==511).
// -------------------------------------------------------------------------
__global__ __launch_bounds__(256) void ccp_coop_kernel(
    const float* __restrict__ rin, const float* __restrict__ tin,
    float* __restrict__ ws, float* __restrict__ acc, float* __restrict__ out)
{
    __shared__ float smem[162 * 64 + 4];   // 41.5 KB; phase1 uses 4416 floats
    const int tid = threadIdx.x;
    const int wv  = tid >> 6;              // wave id 0..3
    const int l   = tid & 63;
    const int bx  = blockIdx.x;

    if (bx == 0 && tid < 2) acc[tid] = 0.0f;   // before grid sync

    // ---------------- phase 1: channel-min + horizontal 35-max ----------
    {
        float (*sm)[4][552] = (float (*)[4][552])smem;   // [2 bufs][4 rows][552]
        const int z = bx >> 4;             // 0..31 (tensor*16 + batch)
        const int b = z & 15;
        const float* __restrict__ in = (z < NB) ? rin : tin;
        const float* __restrict__ pc = in + (size_t)b * 3 * HW;
        const int hbase = (bx & 15) * 32;

        if (tid < 160) {                   // constant -inf halo, both buffers
            int r = tid / 40, j = tid % 40;
            int jj = (j < 20) ? j : (j + 512);
            sm[0][r][jj] = NEG_INF;
            sm[1][r][jj] = NEG_INF;
        }

        f4 ld[2][6];
        {
            const float* pr = pc + (size_t)(hbase + wv) * WID;
            ld[0][0] = NTL((const f4*)pr + l);
            ld[0][1] = NTL((const f4*)(pr + HW) + l);
            ld[0][2] = NTL((const f4*)(pr + 2 * HW) + l);
            ld[0][3] = NTL((const f4*)pr + l + 64);
            ld[0][4] = NTL((const f4*)(pr + HW) + l + 64);
            ld[0][5] = NTL((const f4*)(pr + 2 * HW) + l + 64);
        }
        #pragma unroll
        for (int t = 0; t < 8; ++t) {
            const int cur = t & 1, nxt = cur ^ 1;     // static after unroll
            if (t < 7) {                   // prefetch next task before barrier
                const float* pr = pc + (size_t)(hbase + 4 * (t + 1) + wv) * WID;
                ld[nxt][0] = NTL((const f4*)pr + l);
                ld[nxt][1] = NTL((const f4*)(pr + HW) + l);
                ld[nxt][2] = NTL((const f4*)(pr + 2 * HW) + l);
                ld[nxt][3] = NTL((const f4*)pr + l + 64);
                ld[nxt][4] = NTL((const f4*)(pr + HW) + l + 64);
                ld[nxt][5] = NTL((const f4*)(pr + 2 * HW) + l + 64);
            }
            f4 v0 = min3v(ld[cur][0], ld[cur][1], ld[cur][2]);
            f4 v1 = min3v(ld[cur][3], ld[cur][4], ld[cur][5]);
            float (*S)[552] = sm[cur];
            *(f4*)&S[wv][20 + 4 * l]        = v0;
            *(f4*)&S[wv][20 + 4 * (l + 64)] = v1;
            __syncthreads();               // one barrier/task (ping-pong safe)
            const f4* smr = (const f4*)S[wv];
            f4 o0 = hwin35(smr, l);
            f4 o1 = hwin35(smr, l + 64);
            const int h = hbase + 4 * t + wv;
            f4* wp = (f4*)(ws + (size_t)z * HW + (size_t)h * WID);
            wp[l]      = o0;
            wp[l + 64] = o1;
        }
    }

    __threadfence();
    cg::this_grid().sync();                // replaces kernel boundary

    // ---------------- phase 2: vertical 35-max + |r-t| + reduce ----------
    {
        float (*cm)[64] = (float (*)[64])smem;   // 162 region rows
        float* red = smem + 162 * 64;
        const int col = l;
        const int ty  = wv;                // output rows ty*32 .. ty*32+31
        const int w0  = (bx & 7) * 64;
        const int h0  = ((bx >> 3) & 3) * 128;
        const int b   = bx >> 5;

        float rtv[32];
        float tsum = 0.0f;

        #pragma unroll
        for (int tensor = 0; tensor < 2; ++tensor) {
            const float* __restrict__ pb = ws + (size_t)(tensor * NB + b) * HW;

            for (int i = tid; i < 2592; i += 256) {   // 162 rows x 16 f4
                int r = i >> 4, c4 = i & 15;
                int hh = h0 - 17 + r;
                f4 v = {NEG_INF, NEG_INF, NEG_INF, NEG_INF};
                if (hh >= 0 && hh < HEI)
                    v = ((const f4*)pb)[hh * 128 + (w0 >> 2) + c4];
                *(f4*)&cm[r][4 * c4] = v;
            }
            __syncthreads();

            #pragma unroll
            for (int g = 0; g < 2; ++g) {
                const int base = ty * 32 + g * 16;
                float vc[50];
                #pragma unroll
                for (int i = 0; i < 50; ++i) vc[i] = cm[base + i][col];
                float q[12];
                #pragma unroll
                for (int i = 0; i < 12; ++i)
                    q[i] = fmaxf(fmaxf(vc[4*i], vc[4*i+1]),
                                 fmaxf(vc[4*i+2], vc[4*i+3]));
                #pragma unroll
                for (int m = 0; m < 4; ++m) {
                    float Qc = fmaxf(fmaxf(fmaxf(q[m+1], q[m+2]),
                                           fmaxf(q[m+3], q[m+4])),
                                     fmaxf(fmaxf(q[m+5], q[m+6]), q[m+7]));
                    float A  = fmaxf(Qc, q[m+8]);
                    float o0 = fmaxf(fmaxf(Qc, q[m]),
                                     fmaxf(fmaxf(vc[4*m+32], vc[4*m+33]), vc[4*m+34]));
                    float o1 = fmaxf(A, fmaxf(fmaxf(vc[4*m+1], vc[4*m+2]), vc[4*m+3]));
                    float o2 = fmaxf(A, fmaxf(fmaxf(vc[4*m+2], vc[4*m+3]), vc[4*m+36]));
                    float o3 = fmaxf(A, fmaxf(fmaxf(vc[4*m+3], vc[4*m+36]), vc[4*m+37]));
                    const int k = g * 16 + 4 * m;
                    if (tensor == 0) {
                        rtv[k] = o0; rtv[k+1] = o1; rtv[k+2] = o2; rtv[k+3] = o3;
                    } else {
                        tsum += fabsf(rtv[k]   - o0) + fabsf(rtv[k+1] - o1)
                              + fabsf(rtv[k+2] - o2) + fabsf(rtv[k+3] - o3);
                    }
                }
            }
            __syncthreads();               // protect cm before next staging
        }

        // wave shuffle reduce -> 4 partials -> atomic + ticket finalize
        #pragma unroll
        for (int off = 32; off > 0; off >>= 1)
            tsum += __shfl_down(tsum, off, 64);
        if (col == 0) red[ty] = tsum;
        __syncthreads();
        if (tid == 0) {
            float bs = red[0] + red[1] + red[2] + red[3];
            atomicAdd(acc, bs);
            __threadfence();
            unsigned tk = atomicAdd((unsigned*)(acc + 1), 1u);
            if (tk == 511u) {              // last of 512 blocks
                float s = atomicAdd(acc, 0.0f);
                out[0] = 1.0f / (1.0f + expf(-s / 4194304.0f));
            }
        }
    }
}

// -------------------------------------------------------------------------
extern "C" void kernel_launch(void* const* d_in, const int* in_sizes, int n_in,
                              void* d_out, int out_size, void* d_ws, size_t ws_size,
                              hipStream_t stream) {
    const float* rin = (const float*)d_in[0];   // restored [16,3,512,512]
    const float* tin = (const float*)d_in[1];   // target   [16,3,512,512]
    float* out = (float*)d_out;

    float* wsf = (float*)d_ws;                  // [2][16][512][512] + acc
    float* acc = wsf + (size_t)2 * NB * HW;     // [sum, ticket]

    void* args[5];
    args[0] = (void*)&rin;
    args[1] = (void*)&tin;
    args[2] = (void*)&wsf;
    args[3] = (void*)&acc;
    args[4] = (void*)&out;
    hipLaunchCooperativeKernel((void*)ccp_coop_kernel, dim3(512), dim3(256),
                               args, 0, stream);
}

// Round 11
// 145.363 us; speedup vs baseline: 1.9325x; 1.9325x over previous
//
#include <hip/hip_runtime.h>
#include <math.h>

#define WID 512
#define HEI 512
#define NB  16
#define HW  ((size_t)HEI * WID)
#define NEG_INF (-INFINITY)

typedef float f4 __attribute__((ext_vector_type(4)));

#define NTL(p) __builtin_nontemporal_load(p)

__device__ __forceinline__ float qmax4(f4 v) {
    return fmaxf(fmaxf(v.x, v.y), fmaxf(v.z, v.w));
}

// Horizontal 35-max: output cols 4*c4+d (d=0..3); reads f4 [c4, c4+10]
// (sm float x = image col x-20; halo = -inf). HW-verified R5/R7/R8.
__device__ __forceinline__ f4 hwin35(const f4* __restrict__ rp, int c4) {
    f4 vv[11];
    #pragma unroll
    for (int i = 0; i < 11; ++i) vv[i] = rp[c4 + i];
    float q[10];
    #pragma unroll
    for (int i = 1; i <= 9; ++i) q[i] = qmax4(vv[i]);
    float Q28 = fmaxf(fmaxf(fmaxf(q[2], q[3]), fmaxf(q[4], q[5])),
                      fmaxf(fmaxf(q[6], q[7]), q[8]));
    float Q18 = fmaxf(Q28, q[1]);
    float Q29 = fmaxf(Q28, q[9]);
    float s01 = fmaxf(vv[9].x, vv[9].y);
    float s23 = fmaxf(vv[1].z, vv[1].w);
    f4 o;
    o.x = fmaxf(fmaxf(Q18, vv[0].w), s01);
    o.y = fmaxf(Q18, fmaxf(s01, vv[9].z));
    o.z = fmaxf(fmaxf(Q29, vv[1].y), s23);
    o.w = fmaxf(Q29, fmaxf(s23, vv[10].x));
    return o;
}

// -------------------------------------------------------------------------
// Kernel A: channel-min + horizontal 35-max. R7-verbatim (best measured
// config): 4 rows/block (one wave/row), lane l -> image f4 l and l+64,
// all global/LDS accesses consecutive-lane-consecutive-16B. 4096 blocks
// of pure streaming. Also zeroes acc (R8 addition, dispatch saved).
// -------------------------------------------------------------------------
__global__ __launch_bounds__(256) void hmax_kernel(
    const float* __restrict__ rin, const float* __restrict__ tin,
    float* __restrict__ ws, float* __restrict__ acc)
{
    __shared__ float sm[4][552];     // 20 halo + 512 + 20 halo floats
    const int tid = threadIdx.x;
    const int wv  = tid >> 6;        // wave = row within block
    const int l   = tid & 63;
    const int h   = blockIdx.x * 4 + wv;
    const int z   = blockIdx.y;      // tensor*16 + b
    const int b   = z & 15;
    const float* __restrict__ in = (z < NB) ? rin : tin;
    const float* __restrict__ p  = in + (size_t)b * 3 * HW + (size_t)h * WID;

    if (blockIdx.x == 0 && blockIdx.y == 0 && tid < 2) acc[tid] = 0.0f;

    if (tid < 160) {                 // -inf halo for the block's 4 rows
        int r = tid / 40, j = tid % 40;
        sm[r][(j < 20) ? j : (j + 512)] = NEG_INF;
    }

    const f4* __restrict__ p0 = (const f4*)p;
    const f4* __restrict__ p1 = (const f4*)(p + HW);
    const f4* __restrict__ p2 = (const f4*)(p + 2 * HW);
    f4 a0 = NTL(p0 + l);
    f4 b0 = NTL(p1 + l);
    f4 c0 = NTL(p2 + l);
    f4 a1 = NTL(p0 + l + 64);
    f4 b1 = NTL(p1 + l + 64);
    f4 c1 = NTL(p2 + l + 64);
    f4 v0, v1;
    v0.x = fminf(fminf(a0.x, b0.x), c0.x);
    v0.y = fminf(fminf(a0.y, b0.y), c0.y);
    v0.z = fminf(fminf(a0.z, b0.z), c0.z);
    v0.w = fminf(fminf(a0.w, b0.w), c0.w);
    v1.x = fminf(fminf(a1.x, b1.x), c1.x);
    v1.y = fminf(fminf(a1.y, b1.y), c1.y);
    v1.z = fminf(fminf(a1.z, b1.z), c1.z);
    v1.w = fminf(fminf(a1.w, b1.w), c1.w);
    *(f4*)&sm[wv][20 + 4 * l]        = v0;
    *(f4*)&sm[wv][20 + 4 * (l + 64)] = v1;
    __syncthreads();

    const f4* __restrict__ smr = (const f4*)sm[wv];
    f4 o0 = hwin35(smr, l);
    f4 o1 = hwin35(smr, l + 64);
    f4* __restrict__ wp = (f4*)(ws + (size_t)z * HW + (size_t)h * WID);
    wp[l]      = o0;
    wp[l + 64] = o1;
}

// -------------------------------------------------------------------------
// Kernel B: vertical 35-max, REGISTER-ONLY (no LDS tile, no staging
// barriers): the vertical pass has zero cross-lane sharing, so lane=column
// and each thread computes 32 output rows of one column from 66 region
// values held in registers. Loads are wave-coalesced (consecutive lanes =
// consecutive columns, 256B/wave-load of L2/L3-warm data). Quad-max math
// is byte-identical to the HW-verified R7 block (vc[i] -> v[g*16+i]).
// Grid (2,16,16) = 512 blocks; LDS = 16B -> occupancy VGPR-bound.
// -------------------------------------------------------------------------
__global__ __launch_bounds__(256) void vmax_kernel(
    const float* __restrict__ ws, float* __restrict__ acc,
    float* __restrict__ out)
{
    __shared__ float red[4];
    const int tid = threadIdx.x;
    const int col = blockIdx.x * 256 + tid;   // image column (lane-coalesced)
    const int h0  = blockIdx.y * 32;          // output rows h0..h0+31
    const int b   = blockIdx.z;

    float rtv[32];
    float tsum = 0.0f;

    #pragma unroll 1                          // cap VGPR: one tensor at a time
    for (int tensor = 0; tensor < 2; ++tensor) {
        const float* __restrict__ pb = ws + (size_t)(tensor * NB + b) * HW;

        float v[66];                          // region rows [h0-17, h0+48]
        #pragma unroll
        for (int i = 0; i < 66; ++i) {
            int hh = h0 - 17 + i;             // wave-uniform bounds check
            v[i] = (hh >= 0 && hh < HEI) ? pb[(size_t)hh * WID + col]
                                         : NEG_INF;
        }

        #pragma unroll
        for (int g = 0; g < 2; ++g) {         // outputs h0+16g .. h0+16g+15
            float q[12];
            #pragma unroll
            for (int i = 0; i < 12; ++i)
                q[i] = fmaxf(fmaxf(v[g*16 + 4*i],     v[g*16 + 4*i + 1]),
                             fmaxf(v[g*16 + 4*i + 2], v[g*16 + 4*i + 3]));
            #pragma unroll
            for (int m = 0; m < 4; ++m) {
                float Qc = fmaxf(fmaxf(fmaxf(q[m+1], q[m+2]),
                                       fmaxf(q[m+3], q[m+4])),
                                 fmaxf(fmaxf(q[m+5], q[m+6]), q[m+7]));
                float A  = fmaxf(Qc, q[m+8]);
                float o0 = fmaxf(fmaxf(Qc, q[m]),
                                 fmaxf(fmaxf(v[g*16+4*m+32], v[g*16+4*m+33]),
                                       v[g*16+4*m+34]));
                float o1 = fmaxf(A, fmaxf(fmaxf(v[g*16+4*m+1], v[g*16+4*m+2]),
                                          v[g*16+4*m+3]));
                float o2 = fmaxf(A, fmaxf(fmaxf(v[g*16+4*m+2], v[g*16+4*m+3]),
                                          v[g*16+4*m+36]));
                float o3 = fmaxf(A, fmaxf(fmaxf(v[g*16+4*m+3], v[g*16+4*m+36]),
                                          v[g*16+4*m+37]));
                const int k = g * 16 + 4 * m;
                if (tensor == 0) {
                    rtv[k] = o0; rtv[k+1] = o1; rtv[k+2] = o2; rtv[k+3] = o3;
                } else {
                    tsum += fabsf(rtv[k]   - o0) + fabsf(rtv[k+1] - o1)
                          + fabsf(rtv[k+2] - o2) + fabsf(rtv[k+3] - o3);
                }
            }
        }
    }

    // wave shuffle reduce -> 4 partials -> atomic + ticket finalize
    const int lane = tid & 63;
    const int wv   = tid >> 6;
    #pragma unroll
    for (int off = 32; off > 0; off >>= 1)
        tsum += __shfl_down(tsum, off, 64);
    if (lane == 0) red[wv] = tsum;
    __syncthreads();
    if (tid == 0) {
        float bs = red[0] + red[1] + red[2] + red[3];
        atomicAdd(acc, bs);
        __threadfence();
        unsigned tk = atomicAdd((unsigned*)(acc + 1), 1u);
        if (tk == 511u) {                     // last of 512 blocks
            float s = atomicAdd(acc, 0.0f);   // coherent final sum
            out[0] = 1.0f / (1.0f + expf(-s / 4194304.0f));
        }
    }
}

// -------------------------------------------------------------------------
extern "C" void kernel_launch(void* const* d_in, const int* in_sizes, int n_in,
                              void* d_out, int out_size, void* d_ws, size_t ws_size,
                              hipStream_t stream) {
    const float* rin = (const float*)d_in[0];   // restored [16,3,512,512]
    const float* tin = (const float*)d_in[1];   // target   [16,3,512,512]
    float* out = (float*)d_out;

    float* wsf = (float*)d_ws;                  // [2][16][512][512] + acc
    float* acc = wsf + (size_t)2 * NB * HW;     // [sum, ticket]

    dim3 gA(HEI / 4, 2 * NB);
    hipLaunchKernelGGL(hmax_kernel, gA, dim3(256), 0, stream, rin, tin, wsf, acc);

    dim3 gB(2, 16, NB);
    hipLaunchKernelGGL(vmax_kernel, gB, dim3(256), 0, stream, wsf, acc, out);
}